// Round 9
// baseline (234.328 us; speedup 1.0000x reference)
//
#include <hip/hip_runtime.h>
#include <math.h>

#define NN 256
#define LL 256
#define BB 16384

typedef __attribute__((ext_vector_type(8))) short short8;
typedef __attribute__((ext_vector_type(4))) float f32x4;

// ===========================================================================
// ws layout (bytes):
//   [0, 1 MB)     coef  (float4[65536], plane-arranged, validated r3-r7)
//   [1, 5 MB)     P[8]  (float2[8][65536]) 8 chunk matrices (32 layers each)
//   [5, 7 MB)     Q[4]  (float2[4][65536]) level-1 tree products
//   [1, 2 MB)     R[2]  (float2[2][65536]) level-2 (aliases P0/P1, dead)
//   [2, 3.5 MB)   Wt    (ushort[3][512][512]) bf16x3 W^T (aliases P2-P4, dead)
// ===========================================================================

// --------------------------------------------------------------------------
// Fused coef kernel (validated r7): one block per layer; f64 tables in LDS.
// --------------------------------------------------------------------------
__global__ __launch_bounds__(256) void coefF_kernel(const float* __restrict__ theta,
                                                    const float* __restrict__ phi,
                                                    const float* __restrict__ gamma,
                                                    float4* __restrict__ coef) {
    __shared__ double ipc[128], ips[128], epc[128], eps[128];
    const int l = blockIdx.x;
    const int t = threadIdx.x;
    if (t < 128) {
        double s, c;
        sincos((double)theta[l * 128 + t] * 0.5, &s, &c); ipc[t] = c; ips[t] = s;
        sincos((double)phi[l * 128 + t], &s, &c);         epc[t] = c; eps[t] = s;
    }
    __syncthreads();

    const int j = t;
    const int u = l & 1;
    const int n = (j - u) & 255;
    const int m = n ^ 1;

    auto ipsl = [&](int k, double& re, double& im) {
        k &= 255;
        re = ipc[k >> 1];
        im = (k & 1) ? -ips[k >> 1] : ips[k >> 1];
    };
    double inr, ini, ipr, ipi, imr, imi;
    ipsl(n, inr, ini); ipsl(n + 1, ipr, ipi); ipsl(n - 1, imr, imi);
    double enr = 1.0, eni = 0.0;
    if (!(n & 1)) { enr = epc[n >> 1]; eni = eps[n >> 1]; }
    double dr = 2.0 * inr - ipr - imr;
    double di = 2.0 * ini - ipi - imi;
    double Dre = 0.25 * (enr * dr - eni * di);
    double Dim = 0.25 * (enr * di + eni * dr);
    ipsl(m, inr, ini); ipsl(m + 1, ipr, ipi); ipsl(m - 1, imr, imi);
    int mm = (m - 1) & 255;
    double emr = 1.0, emi = 0.0;
    if (!(mm & 1)) { emr = epc[mm >> 1]; emi = eps[mm >> 1]; }
    double orv = 2.0 * inr + ipr + imr;
    double oiv = 2.0 * ini + ipi + imi;
    double tre = emr * orv - emi * oiv;
    double tim = emr * oiv + emi * orv;
    double Ore = -0.25 * tim;
    double Oim =  0.25 * tre;

    if (l == 0) {
        double s, c;
        sincos((double)gamma[j], &s, &c);
        double a2 = Dre * c - Dim * s, b2 = Dre * s + Dim * c;
        Dre = a2; Dim = b2;
        sincos((double)gamma[j ^ 1], &s, &c);
        a2 = Ore * c - Oim * s; b2 = Ore * s + Oim * c;
        Ore = a2; Oim = b2;
    }
    coef[l * 256 + (j & 7) * 32 + (j >> 3)] =
        make_float4((float)Dre, (float)Dim, (float)Ore, (float)Oim);
}

// Packed complex MZI update (validated rounds 3-7).
__device__ __forceinline__ float2 mzi(float2 cD, float2 cO, float2 y, float2 p) {
    float2 t;
    asm("v_pk_mul_f32 %0, %1, %2 op_sel:[1,1] op_sel_hi:[1,0] neg_lo:[1,0]"
        : "=v"(t) : "v"(cO), "v"(p));
    asm("v_pk_fma_f32 %0, %1, %2, %0 op_sel:[0,0,0] op_sel_hi:[0,1,1]"
        : "+v"(t) : "v"(cO), "v"(p));
    asm("v_pk_fma_f32 %0, %1, %2, %0 op_sel:[1,1,0] op_sel_hi:[1,0,1] neg_lo:[1,0,0]"
        : "+v"(t) : "v"(cD), "v"(y));
    asm("v_pk_fma_f32 %0, %1, %2, %0 op_sel:[0,0,0] op_sel_hi:[0,1,1]"
        : "+v"(t) : "v"(cD), "v"(y));
    return t;
}
__device__ __forceinline__ float2 D_(float4 c) { return make_float2(c.x, c.y); }
__device__ __forceinline__ float2 O_(float4 c) { return make_float2(c.z, c.w); }

// --------------------------------------------------------------------------
// Chunked identity propagation: 8 chunks x 32 layers, 2 basis rows per wave
// (one per lane half).  1024 waves -> 1 per SIMD.  Same validated layer math.
// --------------------------------------------------------------------------
__global__ __launch_bounds__(256) void prop_kernel(const float4* __restrict__ coef,
                                                   float2* __restrict__ Pbase) {
    const int lane = threadIdx.x & 63;
    const int wave = threadIdx.x >> 6;
    const int l32  = lane & 31;
    const int half = lane >> 5;
    const int gid  = blockIdx.x * 4 + wave;      // 0..1023
    const int chunk = gid >> 7;                  // 0..7
    const int row  = ((gid & 127) << 1) | half;  // 0..255
    const int l0   = chunk * 32;
    const int idxL4 = (((lane & 32) | ((lane - 1) & 31))) << 2;
    const int idxR4 = (((lane & 32) | ((lane + 1) & 31))) << 2;

    float2 y[8];
#pragma unroll
    for (int j = 0; j < 8; ++j)
        y[j] = make_float2((8 * l32 + j == row) ? 1.f : 0.f, 0.f);

    const float4* cp = coef + l32;
    auto loadl = [&](int l, float4& c0, float4& c1, float4& c2, float4& c3,
                            float4& c4, float4& c5, float4& c6, float4& c7) {
        const float4* p = cp + l * 256;
        c0 = p[0 * 32]; c1 = p[1 * 32]; c2 = p[2 * 32]; c3 = p[3 * 32];
        c4 = p[4 * 32]; c5 = p[5 * 32]; c6 = p[6 * 32]; c7 = p[7 * 32];
    };

    float4 a0, a1, a2, a3, a4, a5, a6, a7;
    float4 b0, b1, b2, b3, b4, b5, b6, b7;
    loadl(l0, a0, a1, a2, a3, a4, a5, a6, a7);

#pragma unroll 1
    for (int it = 0; it < 16; ++it) {
        loadl(l0 + 2 * it + 1, b0, b1, b2, b3, b4, b5, b6, b7);
        {   // even layer
            float2 t0 = y[0], t1 = y[1], t2 = y[2], t3 = y[3];
            float2 t4 = y[4], t5 = y[5], t6 = y[6], t7 = y[7];
            y[0] = mzi(D_(a0), O_(a0), t0, t1);
            y[1] = mzi(D_(a1), O_(a1), t1, t0);
            y[2] = mzi(D_(a2), O_(a2), t2, t3);
            y[3] = mzi(D_(a3), O_(a3), t3, t2);
            y[4] = mzi(D_(a4), O_(a4), t4, t5);
            y[5] = mzi(D_(a5), O_(a5), t5, t4);
            y[6] = mzi(D_(a6), O_(a6), t6, t7);
            y[7] = mzi(D_(a7), O_(a7), t7, t6);
        }
        if (it < 15) loadl(l0 + 2 * it + 2, a0, a1, a2, a3, a4, a5, a6, a7);
        {   // odd layer
            float2 t0 = y[0], t1 = y[1], t2 = y[2], t3 = y[3];
            float2 t4 = y[4], t5 = y[5], t6 = y[6], t7 = y[7];
            float2 plo, phi2;
            plo.x  = __int_as_float(__builtin_amdgcn_ds_bpermute(idxL4, __float_as_int(t7.x)));
            plo.y  = __int_as_float(__builtin_amdgcn_ds_bpermute(idxL4, __float_as_int(t7.y)));
            phi2.x = __int_as_float(__builtin_amdgcn_ds_bpermute(idxR4, __float_as_int(t0.x)));
            phi2.y = __int_as_float(__builtin_amdgcn_ds_bpermute(idxR4, __float_as_int(t0.y)));
            y[1] = mzi(D_(b1), O_(b1), t1, t2);
            y[2] = mzi(D_(b2), O_(b2), t2, t1);
            y[3] = mzi(D_(b3), O_(b3), t3, t4);
            y[4] = mzi(D_(b4), O_(b4), t4, t3);
            y[5] = mzi(D_(b5), O_(b5), t5, t6);
            y[6] = mzi(D_(b6), O_(b6), t6, t5);
            y[0] = mzi(D_(b0), O_(b0), t0, plo);
            y[7] = mzi(D_(b7), O_(b7), t7, phi2);
        }
    }

    float2* P = Pbase + chunk * 65536;
#pragma unroll
    for (int j = 0; j < 8; ++j)
        P[row * 256 + 8 * l32 + j] = y[j];
}

// --------------------------------------------------------------------------
// Tree combine level: C[m] = A[m] * B[m], complex 256x256 fp32, where
// A = base + m*131072, B = A + 65536, C = out + m*65536.  4 rows per block;
// A-row loads wave-uniform (scalar), B coalesced.  Per-output k-loop order
// identical to the validated combineW accumulation.
// --------------------------------------------------------------------------
__global__ __launch_bounds__(256) void tree_kernel(const float2* __restrict__ base,
                                                   float2* __restrict__ outb) {
    const int mat = blockIdx.x >> 6;
    const int i0  = (blockIdx.x & 63) * 4;
    const int j   = threadIdx.x;
    const float2* A = base + mat * 131072;
    const float2* B = A + 65536;
    float2* C = outb + mat * 65536;

    float acr0 = 0.f, aci0 = 0.f, acr1 = 0.f, aci1 = 0.f;
    float acr2 = 0.f, aci2 = 0.f, acr3 = 0.f, aci3 = 0.f;
#pragma unroll 8
    for (int k = 0; k < 256; ++k) {
        float2 b = B[k * 256 + j];
        float2 a0 = A[(i0 + 0) * 256 + k];
        float2 a1 = A[(i0 + 1) * 256 + k];
        float2 a2 = A[(i0 + 2) * 256 + k];
        float2 a3 = A[(i0 + 3) * 256 + k];
        acr0 += a0.x * b.x - a0.y * b.y;  aci0 += a0.x * b.y + a0.y * b.x;
        acr1 += a1.x * b.x - a1.y * b.y;  aci1 += a1.x * b.y + a1.y * b.x;
        acr2 += a2.x * b.x - a2.y * b.y;  aci2 += a2.x * b.y + a2.y * b.x;
        acr3 += a3.x * b.x - a3.y * b.y;  aci3 += a3.x * b.y + a3.y * b.x;
    }
    C[(i0 + 0) * 256 + j] = make_float2(acr0, aci0);
    C[(i0 + 1) * 256 + j] = make_float2(acr1, aci1);
    C[(i0 + 2) * 256 + j] = make_float2(acr2, aci2);
    C[(i0 + 3) * 256 + j] = make_float2(acr3, aci3);
}

// bf16 RNE + 3-way split (validated r5-r7).
__device__ __forceinline__ unsigned short bf16rne(float f) {
    unsigned int u2 = __float_as_uint(f);
    unsigned int r = (u2 + 0x7FFFu + ((u2 >> 16) & 1u)) >> 16;
    return (unsigned short)r;
}
__device__ __forceinline__ float bf16f(unsigned short h) {
    return __uint_as_float(((unsigned int)h) << 16);
}
__device__ __forceinline__ void split3(float v, unsigned short& h0,
                                       unsigned short& h1, unsigned short& h2) {
    h0 = bf16rne(v);        float r1 = v - bf16f(h0);
    h1 = bf16rne(r1);       float r2 = r1 - bf16f(h1);
    h2 = bf16rne(r2);
}

// --------------------------------------------------------------------------
// Final combine + W split: Cm = R0*R1 (4 rows/block), bf16x3 scatter to Wt.
// --------------------------------------------------------------------------
__global__ __launch_bounds__(256) void combineW_kernel(const float2* __restrict__ R,
                                                       unsigned short* __restrict__ Wt) {
    const int i0 = blockIdx.x * 4;
    const int j  = threadIdx.x;
    const float2* A = R;
    const float2* B = R + 65536;

    float acr[4] = {0.f, 0.f, 0.f, 0.f};
    float aci[4] = {0.f, 0.f, 0.f, 0.f};
#pragma unroll 8
    for (int k = 0; k < 256; ++k) {
        float2 b = B[k * 256 + j];
#pragma unroll
        for (int r = 0; r < 4; ++r) {
            float2 a = A[(i0 + r) * 256 + k];
            acr[r] += a.x * b.x - a.y * b.y;
            aci[r] += a.x * b.y + a.y * b.x;
        }
    }
    unsigned short* W0 = Wt;
    unsigned short* W1 = Wt + 262144;
    unsigned short* W2 = Wt + 524288;
#pragma unroll
    for (int r = 0; r < 4; ++r) {
        const int i = i0 + r;
        unsigned short r0, r1, r2, i0s, i1s, i2s, n0, n1, n2;
        split3(acr[r], r0, r1, r2);
        split3(aci[r], i0s, i1s, i2s);
        split3(-aci[r], n0, n1, n2);
        W0[j * 512 + i] = r0;           W1[j * 512 + i] = r1;           W2[j * 512 + i] = r2;
        W0[(j + 256) * 512 + i] = i0s;  W1[(j + 256) * 512 + i] = i1s;  W2[(j + 256) * 512 + i] = i2s;
        W0[j * 512 + i + 256] = n0;     W1[j * 512 + i + 256] = n1;     W2[j * 512 + i + 256] = n2;
        W0[(j + 256) * 512 + i + 256] = r0;
        W1[(j + 256) * 512 + i + 256] = r1;
        W2[(j + 256) * 512 + i + 256] = r2;
    }
}

// --------------------------------------------------------------------------
// Main GEMM — EXACT r5/r7 structure (60 µs verified).
// --------------------------------------------------------------------------
__global__ __launch_bounds__(256, 2) void gemm_kernel(
        const float* __restrict__ x_re, const float* __restrict__ x_im,
        const unsigned short* __restrict__ Wt, float* __restrict__ out) {
    __shared__ unsigned short XL[3][128][40];
    __shared__ unsigned short WL[3][128][40];

    const int t    = threadIdx.x;
    const int lane = t & 63;
    const int wave = t >> 6;
    const int wm   = wave >> 1, wn = wave & 1;
    const int nt = blockIdx.x & 3, mt = blockIdx.x >> 2;
    const int m0 = mt * 128, n0 = nt * 128;
    const int lr = lane & 15, lg = lane >> 4;

    f32x4 acc[4][4];
#pragma unroll
    for (int a = 0; a < 4; ++a)
#pragma unroll
        for (int b = 0; b < 4; ++b) acc[a][b] = (f32x4)0.f;

#pragma unroll 1
    for (int ks = 0; ks < 16; ++ks) {
        const int k0 = ks * 32;
        const float* xsrc = (k0 < 256) ? x_re : x_im;
        const int kcol = k0 & 255;
#pragma unroll
        for (int r = 0; r < 4; ++r) {
            int F = r * 256 + t;
            int row = F >> 3, g = F & 7;
            float4 v = ((const float4*)xsrc)[(m0 + row) * 64 + (kcol >> 2) + g];
            unsigned short h0[4], h1[4], h2[4];
            split3(v.x, h0[0], h1[0], h2[0]);
            split3(v.y, h0[1], h1[1], h2[1]);
            split3(v.z, h0[2], h1[2], h2[2]);
            split3(v.w, h0[3], h1[3], h2[3]);
            *(ushort4*)&XL[0][row][g * 4] = make_ushort4(h0[0], h0[1], h0[2], h0[3]);
            *(ushort4*)&XL[1][row][g * 4] = make_ushort4(h1[0], h1[1], h1[2], h1[3]);
            *(ushort4*)&XL[2][row][g * 4] = make_ushort4(h2[0], h2[1], h2[2], h2[3]);
        }
#pragma unroll
        for (int r = 0; r < 6; ++r) {
            int U = r * 256 + t;
            int p = U >> 9, rem = U & 511;
            int n = rem >> 2, ku = (rem & 3) * 8;
            uint4 v = ((const uint4*)Wt)[p * 32768 + (n0 + n) * 64 + ((k0 + ku) >> 3)];
            *(uint4*)&WL[p][n][ku] = v;
        }
        __syncthreads();

        short8 bfr[3][4];
#pragma unroll
        for (int p = 0; p < 3; ++p)
#pragma unroll
            for (int ni = 0; ni < 4; ++ni)
                bfr[p][ni] = *(const short8*)&WL[p][wn * 64 + ni * 16 + lr][lg * 8];

#pragma unroll
        for (int i = 0; i < 3; ++i) {
            short8 af[4];
#pragma unroll
            for (int mi = 0; mi < 4; ++mi)
                af[mi] = *(const short8*)&XL[i][wm * 64 + mi * 16 + lr][lg * 8];
#pragma unroll
            for (int jj = 0; jj < 3; ++jj) {
                if (i + jj > 2) continue;
#pragma unroll
                for (int mi = 0; mi < 4; ++mi)
#pragma unroll
                    for (int ni = 0; ni < 4; ++ni)
                        acc[mi][ni] = __builtin_amdgcn_mfma_f32_16x16x32_bf16(
                            af[mi], bfr[jj][ni], acc[mi][ni], 0, 0, 0);
            }
        }
        __syncthreads();
    }

#pragma unroll
    for (int mi = 0; mi < 4; ++mi) {
#pragma unroll
        for (int ni = 0; ni < 4; ++ni) {
            int nglob = n0 + wn * 64 + ni * 16 + lr;
            float* dst = (nglob < 256)
                       ? out + (size_t)nglob
                       : out + (size_t)BB * 256 + (nglob - 256);
#pragma unroll
            for (int e = 0; e < 4; ++e) {
                int m = m0 + wm * 64 + mi * 16 + lg * 4 + e;
                dst[(size_t)m * 256] = acc[mi][ni][e];
            }
        }
    }
}

extern "C" void kernel_launch(void* const* d_in, const int* in_sizes, int n_in,
                              void* d_out, int out_size, void* d_ws, size_t ws_size,
                              hipStream_t stream) {
    const float* x_re  = (const float*)d_in[0];
    const float* x_im  = (const float*)d_in[1];
    const float* theta = (const float*)d_in[2];
    const float* phi   = (const float*)d_in[3];
    const float* gamma = (const float*)d_in[4];

    char* ws = (char*)d_ws;
    float4* coef        = (float4*)ws;                          // [0, 1 MB)
    float2* P           = (float2*)(ws + (1 << 20));            // [1, 5 MB)
    float2* Q           = (float2*)(ws + (5 << 20));            // [5, 7 MB)
    float2* R           = (float2*)(ws + (1 << 20));            // alias P0/P1
    unsigned short* Wt  = (unsigned short*)(ws + (2 << 20));    // alias P2-P4

    hipLaunchKernelGGL(coefF_kernel, dim3(256), dim3(256), 0, stream,
                       theta, phi, gamma, coef);
    hipLaunchKernelGGL(prop_kernel, dim3(256), dim3(256), 0, stream, coef, P);
    hipLaunchKernelGGL(tree_kernel, dim3(256), dim3(256), 0, stream, P, Q);  // Q[m]=P[2m]*P[2m+1]
    hipLaunchKernelGGL(tree_kernel, dim3(128), dim3(256), 0, stream, Q, R);  // R[m]=Q[2m]*Q[2m+1]
    hipLaunchKernelGGL(combineW_kernel, dim3(64), dim3(256), 0, stream, R, Wt);
    hipLaunchKernelGGL(gemm_kernel, dim3(512), dim3(256), 0, stream,
                       x_re, x_im, Wt, (float*)d_out);
}